// Round 1
// baseline (1081.223 us; speedup 1.0000x reference)
//
#include <hip/hip_runtime.h>
#include <hip/hip_bf16.h>

typedef __attribute__((ext_vector_type(8))) short bf16x8;
typedef __attribute__((ext_vector_type(4))) float f32x4;
typedef __attribute__((ext_vector_type(4))) unsigned int uint4v;

#define B_ 16
#define C_ 768
#define N_ 4096
#define M_ 1024

// ---------------------------------------------------------------------------
// prep_mem: memory (M,C) fp32 -> mem_bf (M,C) bf16, memT (C,M) bf16, rm = 1/||mem_m||
// grid: M_ blocks x 256 threads
// ---------------------------------------------------------------------------
__global__ __launch_bounds__(256) void prep_mem_kernel(
    const float* __restrict__ mem, __hip_bfloat16* __restrict__ mem_bf,
    __hip_bfloat16* __restrict__ memT, float* __restrict__ rm)
{
  const int m = blockIdx.x;
  const int t = threadIdx.x;
  float ss = 0.f;
  for (int c = t; c < C_; c += 256) {
    float v = mem[(size_t)m * C_ + c];
    ss += v * v;
    __hip_bfloat16 h = __float2bfloat16(v);
    mem_bf[(size_t)m * C_ + c] = h;
    memT[(size_t)c * M_ + m] = h;
  }
  #pragma unroll
  for (int off = 1; off < 64; off <<= 1) ss += __shfl_xor(ss, off, 64);
  __shared__ float sred[4];
  if ((t & 63) == 0) sred[t >> 6] = ss;
  __syncthreads();
  if (t == 0) {
    float tot = sred[0] + sred[1] + sred[2] + sred[3];
    rm[m] = 1.f / fmaxf(sqrtf(tot), 1e-12f);
  }
}

// ---------------------------------------------------------------------------
// prep_z: z (B,C,N) fp32 -> zb (B,N,C) bf16 (LDS tile transpose) + rz = 1/||z_row||
// grid: B_*(N_/64) blocks x 256 threads; block = (b, 64 n-rows), loops full C.
// ---------------------------------------------------------------------------
__global__ __launch_bounds__(256) void prep_z_kernel(
    const float* __restrict__ z, __hip_bfloat16* __restrict__ zb, float* __restrict__ rz)
{
  const int bid = blockIdx.x;
  const int b = bid >> 6;
  const int n0 = (bid & 63) << 6;
  const int t = threadIdx.x;
  __shared__ float tile[64][65];   // [c][n], padded
  __shared__ float red[64][4];
  const int nr = t & 63, cr = t >> 6;      // read coords: n = n0+nr, c-row subset cr+4i
  const int nw = t >> 2, cw = (t & 3) << 4; // write coords: n = n0+nw, c cols cw..cw+15
  float ss = 0.f;
  const float* zp = z + ((size_t)b * C_) * N_ + n0 + nr;
  __hip_bfloat16* zo = zb + ((size_t)(b * N_ + n0 + nw)) * C_ + cw;
  for (int c0 = 0; c0 < C_; c0 += 64) {
    #pragma unroll
    for (int i = 0; i < 16; ++i) {
      float v = zp[(size_t)(c0 + cr + i * 4) * N_];
      tile[cr + i * 4][nr] = v;
      ss += v * v;            // thread's n fixed (=nr); covers c ≡ cr (mod 4)
    }
    __syncthreads();
    alignas(16) __hip_bfloat16 hh[16];
    #pragma unroll
    for (int i = 0; i < 16; ++i) hh[i] = __float2bfloat16(tile[cw + i][nw]);
    *(uint4v*)(zo + c0) = *(const uint4v*)(hh);       // 16 bf16 = 32B contiguous
    *(uint4v*)(zo + c0 + 8) = *(const uint4v*)(hh + 8);
    __syncthreads();
  }
  red[nr][cr] = ss;
  __syncthreads();
  if (t < 64) {
    float tot = red[t][0] + red[t][1] + red[t][2] + red[t][3];
    rz[(size_t)b * N_ + n0 + t] = 1.f / fmaxf(sqrtf(tot), 1e-12f);
  }
}

// ---------------------------------------------------------------------------
// fused_attn: per block (b, 64 q-rows): scores(64x1024) -> softmax -> attn out
//             -> z_hat(64x768) with transposed store.
// 512 threads = 8 waves. Phase1: wave w owns m-chunk [w*128, w*128+128).
// Phase2: wave w owns c-chunk [w*96, w*96+96). attn staged bf16 in swizzled LDS.
// ---------------------------------------------------------------------------
#define SMEM_BYTES 137728
#define O_RED 131072          // [64 rows][8 waves] f32
#define O_FIN 133120          // [64] f32
#define O_SRZ 133376          // [64] f32
#define O_SRM 133632          // [1024] f32

__global__ __launch_bounds__(512, 2) void fused_attn_kernel(
    const __hip_bfloat16* __restrict__ zb, const __hip_bfloat16* __restrict__ mem_bf,
    const __hip_bfloat16* __restrict__ memT, const float* __restrict__ rz,
    const float* __restrict__ rm, float* __restrict__ out_z, float* __restrict__ out_a)
{
  extern __shared__ char smem[];
  const int b = blockIdx.x >> 6;
  const int n0 = (blockIdx.x & 63) << 6;
  const int t = threadIdx.x;
  const int w = t >> 6, l = t & 63, g = l >> 4, lm = l & 15;

  float* srz = (float*)(smem + O_SRZ);
  float* srm = (float*)(smem + O_SRM);
  if (t < 64) srz[t] = rz[(size_t)b * N_ + n0 + t];
  srm[t] = rm[t];
  srm[t + 512] = rm[t + 512];

  const int m0 = w << 7;
  f32x4 acc[4][8];
  #pragma unroll
  for (int qf = 0; qf < 4; ++qf)
    #pragma unroll
    for (int mf = 0; mf < 8; ++mf) {
      acc[qf][mf][0] = 0.f; acc[qf][mf][1] = 0.f;
      acc[qf][mf][2] = 0.f; acc[qf][mf][3] = 0.f;
    }

  // Phase 1: scores = zb(64xC) @ mem_bf^T(CxM). A row = q, B col = m; both
  // operands K-contiguous in their layouts -> direct 16B global frag loads.
  const __hip_bfloat16* ap = zb + ((size_t)(b * N_ + n0 + lm)) * C_ + g * 8;
  const __hip_bfloat16* bp = mem_bf + ((size_t)(m0 + lm)) * C_ + g * 8;
  #pragma unroll 1
  for (int k = 0; k < C_; k += 32) {
    bf16x8 af[4], bfr[8];
    #pragma unroll
    for (int qf = 0; qf < 4; ++qf) af[qf] = *(const bf16x8*)(ap + (size_t)qf * 16 * C_ + k);
    #pragma unroll
    for (int mf = 0; mf < 8; ++mf) bfr[mf] = *(const bf16x8*)(bp + (size_t)mf * 16 * C_ + k);
    #pragma unroll
    for (int qf = 0; qf < 4; ++qf)
      #pragma unroll
      for (int mf = 0; mf < 8; ++mf)
        acc[qf][mf] = __builtin_amdgcn_mfma_f32_16x16x32_bf16(af[qf], bfr[mf], acc[qf][mf], 0, 0, 0);
  }

  __syncthreads();   // srz/srm staged; LDS free for reductions

  // scale: s = dot * (1/||z||) * (1/||mem||)
  float scm[8];
  #pragma unroll
  for (int mf = 0; mf < 8; ++mf) scm[mf] = srm[m0 + mf * 16 + lm];
  float scr[4][4];
  #pragma unroll
  for (int qf = 0; qf < 4; ++qf)
    #pragma unroll
    for (int j = 0; j < 4; ++j) scr[qf][j] = srz[qf * 16 + g * 4 + j];
  #pragma unroll
  for (int qf = 0; qf < 4; ++qf)
    #pragma unroll
    for (int mf = 0; mf < 8; ++mf)
      #pragma unroll
      for (int j = 0; j < 4; ++j)
        acc[qf][mf][j] *= scr[qf][j] * scm[mf];

  // row max: per-lane over 8 m-frags, then across the 16 lanes of the group
  float rx[4][4];
  #pragma unroll
  for (int qf = 0; qf < 4; ++qf)
    #pragma unroll
    for (int j = 0; j < 4; ++j) {
      float v = -3.4e38f;
      #pragma unroll
      for (int mf = 0; mf < 8; ++mf) v = fmaxf(v, acc[qf][mf][j]);
      rx[qf][j] = v;
    }
  #pragma unroll
  for (int off = 1; off < 16; off <<= 1)
    #pragma unroll
    for (int qf = 0; qf < 4; ++qf)
      #pragma unroll
      for (int j = 0; j < 4; ++j)
        rx[qf][j] = fmaxf(rx[qf][j], __shfl_xor(rx[qf][j], off, 64));

  float* red = (float*)(smem + O_RED);
  float* fin = (float*)(smem + O_FIN);
  if (lm == 0) {
    #pragma unroll
    for (int qf = 0; qf < 4; ++qf)
      #pragma unroll
      for (int j = 0; j < 4; ++j)
        red[(qf * 16 + g * 4 + j) * 8 + w] = rx[qf][j];
  }
  __syncthreads();
  if (t < 64) {
    float v = -3.4e38f;
    #pragma unroll
    for (int i = 0; i < 8; ++i) v = fmaxf(v, red[t * 8 + i]);
    fin[t] = v;
  }
  __syncthreads();
  float mx[4][4];
  #pragma unroll
  for (int qf = 0; qf < 4; ++qf)
    #pragma unroll
    for (int j = 0; j < 4; ++j) mx[qf][j] = fin[qf * 16 + g * 4 + j];

  // exp + row sum
  float ps[4][4];
  #pragma unroll
  for (int qf = 0; qf < 4; ++qf)
    #pragma unroll
    for (int j = 0; j < 4; ++j) ps[qf][j] = 0.f;
  #pragma unroll
  for (int qf = 0; qf < 4; ++qf)
    #pragma unroll
    for (int mf = 0; mf < 8; ++mf)
      #pragma unroll
      for (int j = 0; j < 4; ++j) {
        float p = __expf(acc[qf][mf][j] - mx[qf][j]);
        acc[qf][mf][j] = p;
        ps[qf][j] += p;
      }
  #pragma unroll
  for (int off = 1; off < 16; off <<= 1)
    #pragma unroll
    for (int qf = 0; qf < 4; ++qf)
      #pragma unroll
      for (int j = 0; j < 4; ++j)
        ps[qf][j] += __shfl_xor(ps[qf][j], off, 64);
  if (lm == 0) {
    #pragma unroll
    for (int qf = 0; qf < 4; ++qf)
      #pragma unroll
      for (int j = 0; j < 4; ++j)
        red[(qf * 16 + g * 4 + j) * 8 + w] = ps[qf][j];
  }
  __syncthreads();
  if (t < 64) {
    float v = 0.f;
    #pragma unroll
    for (int i = 0; i < 8; ++i) v += red[t * 8 + i];
    fin[t] = 1.f / v;   // >= 1 always (max-subtracted)
  }
  __syncthreads();
  float ri[4][4];
  #pragma unroll
  for (int qf = 0; qf < 4; ++qf)
    #pragma unroll
    for (int j = 0; j < 4; ++j) ri[qf][j] = fin[qf * 16 + g * 4 + j];

  // write attn (fp32 global) + bf16 swizzled LDS tile pa[64][1024]
  char* pa = smem;
  float* oa = out_a + ((size_t)(b * N_ + n0)) * M_ + m0;
  #pragma unroll
  for (int qf = 0; qf < 4; ++qf)
    #pragma unroll
    for (int mf = 0; mf < 8; ++mf)
      #pragma unroll
      for (int j = 0; j < 4; ++j) {
        const int row = qf * 16 + g * 4 + j;
        float v = acc[qf][mf][j] * ri[qf][j];
        oa[(size_t)row * M_ + mf * 16 + lm] = v;
        int off = (row * 2048 + (m0 + mf * 16 + lm) * 2) ^ ((row & 7) << 4);
        *(__hip_bfloat16*)(pa + off) = __float2bfloat16(v);
      }
  __syncthreads();

  // Phase 2: z_hat = attn(64xM) @ memory(MxC); B frags K-contiguous from memT.
  const int c0 = w * 96;
  f32x4 acc2[4][6];
  #pragma unroll
  for (int qf = 0; qf < 4; ++qf)
    #pragma unroll
    for (int cf = 0; cf < 6; ++cf) {
      acc2[qf][cf][0] = 0.f; acc2[qf][cf][1] = 0.f;
      acc2[qf][cf][2] = 0.f; acc2[qf][cf][3] = 0.f;
    }
  const __hip_bfloat16* bp2 = memT + ((size_t)(c0 + lm)) * M_ + g * 8;
  #pragma unroll 1
  for (int k = 0; k < M_; k += 32) {
    bf16x8 a2[4], b2[6];
    #pragma unroll
    for (int qf = 0; qf < 4; ++qf) {
      const int row = qf * 16 + lm;
      const int off = (row * 2048 + (k + g * 8) * 2) ^ ((row & 7) << 4);
      a2[qf] = *(const bf16x8*)(pa + off);
    }
    #pragma unroll
    for (int cf = 0; cf < 6; ++cf) b2[cf] = *(const bf16x8*)(bp2 + (size_t)cf * 16 * M_ + k);
    #pragma unroll
    for (int qf = 0; qf < 4; ++qf)
      #pragma unroll
      for (int cf = 0; cf < 6; ++cf)
        acc2[qf][cf] = __builtin_amdgcn_mfma_f32_16x16x32_bf16(a2[qf], b2[cf], acc2[qf][cf], 0, 0, 0);
  }

  // transposed store: out_z[b][c][n], 4 consecutive n per lane-frag -> f32x4
  float* oz = out_z + (size_t)b * C_ * N_ + n0;
  #pragma unroll
  for (int qf = 0; qf < 4; ++qf)
    #pragma unroll
    for (int cf = 0; cf < 6; ++cf) {
      const int c = c0 + cf * 16 + lm;
      *(f32x4*)(oz + (size_t)c * N_ + qf * 16 + g * 4) = acc2[qf][cf];
    }
}

// ---------------------------------------------------------------------------
extern "C" void kernel_launch(void* const* d_in, const int* in_sizes, int n_in,
                              void* d_out, int out_size, void* d_ws, size_t ws_size,
                              hipStream_t stream) {
  const float* z = (const float*)d_in[0];
  const float* mem = (const float*)d_in[1];
  float* out_z = (float*)d_out;
  float* out_a = out_z + (size_t)B_ * C_ * N_;

  char* ws = (char*)d_ws;
  __hip_bfloat16* zb     = (__hip_bfloat16*)ws;                         // 96 MB
  __hip_bfloat16* mem_bf = (__hip_bfloat16*)(ws + (size_t)100663296);   // 1.5 MB
  __hip_bfloat16* memT   = (__hip_bfloat16*)(ws + (size_t)100663296 + 1572864);
  float* rz              = (float*)(ws + (size_t)100663296 + 2 * 1572864);
  float* rm              = (float*)(ws + (size_t)100663296 + 2 * 1572864 + 262144);

  (void)hipFuncSetAttribute((const void*)fused_attn_kernel,
                            hipFuncAttributeMaxDynamicSharedMemorySize, SMEM_BYTES);

  prep_mem_kernel<<<dim3(M_), dim3(256), 0, stream>>>(mem, mem_bf, memT, rm);
  prep_z_kernel<<<dim3(B_ * (N_ / 64)), dim3(256), 0, stream>>>(z, zb, rz);
  fused_attn_kernel<<<dim3(B_ * (N_ / 64)), dim3(512), SMEM_BYTES, stream>>>(
      zb, mem_bf, memT, rz, rm, out_z, out_a);
}

// Round 3
// 1009.015 us; speedup vs baseline: 1.0716x; 1.0716x over previous
//
#include <hip/hip_runtime.h>
#include <hip/hip_bf16.h>

typedef __attribute__((ext_vector_type(8))) short bf16x8;
typedef __attribute__((ext_vector_type(4))) short short4v;
typedef __attribute__((ext_vector_type(4))) float f32x4;
typedef __attribute__((ext_vector_type(16))) float f32x16;
typedef __attribute__((ext_vector_type(4))) unsigned int uint4v;

#define B_ 16
#define C_ 768
#define N_ 4096
#define M_ 1024

// ---------------------------------------------------------------------------
// prep_mem: memory (M,C) fp32 -> mem_bf (M,C) bf16, memT (C,M) bf16, rm=1/||m||
// ---------------------------------------------------------------------------
__global__ __launch_bounds__(256) void prep_mem_kernel(
    const float* __restrict__ mem, __hip_bfloat16* __restrict__ mem_bf,
    __hip_bfloat16* __restrict__ memT, float* __restrict__ rm)
{
  const int m = blockIdx.x;
  const int t = threadIdx.x;
  float ss = 0.f;
  for (int c = t; c < C_; c += 256) {
    float v = mem[(size_t)m * C_ + c];
    ss += v * v;
    __hip_bfloat16 h = __float2bfloat16(v);
    mem_bf[(size_t)m * C_ + c] = h;
    memT[(size_t)c * M_ + m] = h;
  }
  #pragma unroll
  for (int off = 1; off < 64; off <<= 1) ss += __shfl_xor(ss, off, 64);
  __shared__ float sred[4];
  if ((t & 63) == 0) sred[t >> 6] = ss;
  __syncthreads();
  if (t == 0) {
    float tot = sred[0] + sred[1] + sred[2] + sred[3];
    rm[m] = 1.f / fmaxf(sqrtf(tot), 1e-12f);
  }
}

// ---------------------------------------------------------------------------
// prep_z: z (B,C,N) fp32 -> zb (B,N,C) bf16 + rz = 1/||z_row||; f32x4 reads.
// ---------------------------------------------------------------------------
__global__ __launch_bounds__(256) void prep_z_kernel(
    const float* __restrict__ z, __hip_bfloat16* __restrict__ zb, float* __restrict__ rz)
{
  const int bid = blockIdx.x;
  const int b = bid >> 6;
  const int n0 = (bid & 63) << 6;
  const int t = threadIdx.x;
  __shared__ float tile[64][68];     // [c-sub][n]
  __shared__ float red[64][16];
  const int cr = t >> 4;             // 0..15
  const int n4 = (t & 15) * 4;
  const int nw = t >> 2;             // 0..63
  const int cq = (t & 3) * 16;
  float ss0 = 0, ss1 = 0, ss2 = 0, ss3 = 0;
  const float* zp = z + (size_t)b * C_ * N_ + n0 + n4;
  for (int c0 = 0; c0 < C_; c0 += 64) {
    #pragma unroll
    for (int i = 0; i < 4; ++i) {
      const int c = cr + i * 16;
      f32x4 v = *(const f32x4*)(zp + (size_t)(c0 + c) * N_);
      *(f32x4*)&tile[c][n4] = v;
      ss0 += v[0] * v[0]; ss1 += v[1] * v[1];
      ss2 += v[2] * v[2]; ss3 += v[3] * v[3];
    }
    __syncthreads();
    alignas(16) __hip_bfloat16 hh[16];
    #pragma unroll
    for (int i = 0; i < 16; ++i) hh[i] = __float2bfloat16(tile[cq + i][nw]);
    __hip_bfloat16* zo = zb + (size_t)(b * N_ + n0 + nw) * C_ + c0 + cq;
    *(uint4v*)zo = *(const uint4v*)hh;
    *(uint4v*)(zo + 8) = *(const uint4v*)(hh + 8);
    __syncthreads();
  }
  red[n4 + 0][cr] = ss0; red[n4 + 1][cr] = ss1;
  red[n4 + 2][cr] = ss2; red[n4 + 3][cr] = ss3;
  __syncthreads();
  if (t < 64) {
    float s = 0.f;
    #pragma unroll
    for (int i = 0; i < 16; ++i) s += red[t][i];
    rz[(size_t)b * N_ + n0 + t] = 1.f / fmaxf(sqrtf(s), 1e-12f);
  }
}

// ---------------------------------------------------------------------------
// fused_attn: block = (b, 64 q-rows), 1024 threads = 16 waves.
// Phase 1 (32x32x16 MFMA): A (z rows) from swizzled LDS tile, B from global.
//   wave w owns m-chunk [w*64, w*64+64).  No max-subtraction (cosine-bounded).
// Epilogue: cross-wave row-sum, normalized P -> bf16 swizzled LDS (over A-tile).
// Phase 2 (16x16x32 MFMA): wave w owns c-chunk [w*48,+48); attn fp32 written
//   via vectorized LDS roundtrip interleaved into the K-loop.
// ---------------------------------------------------------------------------
#define SMEM_BYTES 139776
#define O_RED 131072   // [64][16] f32
#define O_FIN 135168   // [64] f32
#define O_SRZ 135424   // [64] f32
#define O_SRM 135680   // [1024] f32

__global__ __launch_bounds__(1024, 4) void fused_attn_kernel(
    const __hip_bfloat16* __restrict__ zb, const __hip_bfloat16* __restrict__ mem_bf,
    const __hip_bfloat16* __restrict__ memT, const float* __restrict__ rz,
    const float* __restrict__ rm, float* __restrict__ out_z, float* __restrict__ out_a)
{
  extern __shared__ char smem[];
  const int b = blockIdx.x >> 6;
  const int n0 = (blockIdx.x & 63) << 6;
  const int t = threadIdx.x;
  const int w = t >> 6, l = t & 63, lo = l & 31, hi = l >> 5;

  // ---- stage A-tile (64 x 768 bf16, swizzled) ----
  {
    const int row = t >> 4;
    const __hip_bfloat16* src = zb + (size_t)(b * N_ + n0 + row) * C_;
    char* dst = smem + row * 1536;
    #pragma unroll
    for (int p = 0; p < 6; ++p) {
      const int unit = (t & 15) + p * 16;
      bf16x8 v = *(const bf16x8*)(src + unit * 8);
      *(bf16x8*)(dst + ((unit * 16) ^ ((row & 15) << 4))) = v;
    }
  }
  float* srz = (float*)(smem + O_SRZ);
  float* srm = (float*)(smem + O_SRM);
  if (t < 64) srz[t] = rz[(size_t)b * N_ + n0 + t];
  srm[t] = rm[t];
  __syncthreads();

  // ---- phase 1: scores ----
  const int m0 = w << 6;
  f32x16 acc[2][2];
  #pragma unroll
  for (int qf = 0; qf < 2; ++qf)
    #pragma unroll
    for (int mf = 0; mf < 2; ++mf)
      #pragma unroll
      for (int j = 0; j < 16; ++j) acc[qf][mf][j] = 0.f;

  const char* At = smem;
  const __hip_bfloat16* bp = mem_bf + (size_t)(m0 + lo) * C_ + hi * 8;
  #pragma unroll
  for (int kk = 0; kk < C_; kk += 16) {
    bf16x8 a0, a1, bb0, bb1;
    {
      const int r0 = lo;                 // qf=0 rows
      a0 = *(const bf16x8*)(At + r0 * 1536 + (((kk + hi * 8) * 2) ^ ((r0 & 15) << 4)));
      const int r1 = 32 + lo;            // qf=1 rows
      a1 = *(const bf16x8*)(At + r1 * 1536 + (((kk + hi * 8) * 2) ^ ((r1 & 15) << 4)));
    }
    bb0 = *(const bf16x8*)(bp + kk);
    bb1 = *(const bf16x8*)(bp + (size_t)32 * C_ + kk);
    acc[0][0] = __builtin_amdgcn_mfma_f32_32x32x16_bf16(a0, bb0, acc[0][0], 0, 0, 0);
    acc[0][1] = __builtin_amdgcn_mfma_f32_32x32x16_bf16(a0, bb1, acc[0][1], 0, 0, 0);
    acc[1][0] = __builtin_amdgcn_mfma_f32_32x32x16_bf16(a1, bb0, acc[1][0], 0, 0, 0);
    acc[1][1] = __builtin_amdgcn_mfma_f32_32x32x16_bf16(a1, bb1, acc[1][1], 0, 0, 0);
  }

  // ---- epilogue: scale -> exp -> cross-wave row-sum -> normalized bf16 P ----
  float scm0 = srm[m0 + lo], scm1 = srm[m0 + 32 + lo];
  float rs[2][16];
  #pragma unroll
  for (int qf = 0; qf < 2; ++qf)
    #pragma unroll
    for (int r = 0; r < 16; ++r) {
      const int row = qf * 32 + (r & 3) + 8 * (r >> 2) + 4 * hi;
      const float sz = srz[row];
      float p0 = __expf(acc[qf][0][r] * sz * scm0);
      float p1 = __expf(acc[qf][1][r] * sz * scm1);
      acc[qf][0][r] = p0;
      acc[qf][1][r] = p1;
      rs[qf][r] = p0 + p1;
    }
  #pragma unroll
  for (int off = 1; off < 32; off <<= 1)
    #pragma unroll
    for (int qf = 0; qf < 2; ++qf)
      #pragma unroll
      for (int r = 0; r < 16; ++r)
        rs[qf][r] += __shfl_xor(rs[qf][r], off, 64);

  float* red = (float*)(smem + O_RED);
  float* fin = (float*)(smem + O_FIN);
  if (lo == 0) {
    #pragma unroll
    for (int qf = 0; qf < 2; ++qf)
      #pragma unroll
      for (int r = 0; r < 16; ++r) {
        const int row = qf * 32 + (r & 3) + 8 * (r >> 2) + 4 * hi;
        red[row * 16 + w] = rs[qf][r];
      }
  }
  __syncthreads();
  if (t < 64) {
    float s = 0.f;
    #pragma unroll
    for (int i = 0; i < 16; ++i) s += red[t * 16 + i];
    fin[t] = 1.f / s;
  }
  __syncthreads();

  // write normalized P as bf16 into swizzled LDS (overwrites A-tile region)
  char* Pt = smem;
  #pragma unroll
  for (int qf = 0; qf < 2; ++qf)
    #pragma unroll
    for (int r = 0; r < 16; ++r) {
      const int row = qf * 32 + (r & 3) + 8 * (r >> 2) + 4 * hi;
      const float riv = fin[row];
      #pragma unroll
      for (int mf = 0; mf < 2; ++mf) {
        const int col = m0 + mf * 32 + lo;
        const int off = (row * 2048 + ((col * 2) ^ ((row & 15) << 4)));
        *(__hip_bfloat16*)(Pt + off) = __float2bfloat16(acc[qf][mf][r] * riv);
      }
    }
  __syncthreads();

  // ---- phase 2: z_hat = P @ memory, + interleaved vectorized attn stores ----
  const int c0 = w * 48;
  const int lm = l & 15, g = l >> 4;
  f32x4 acc2[4][3];
  #pragma unroll
  for (int qf = 0; qf < 4; ++qf)
    #pragma unroll
    for (int cf = 0; cf < 3; ++cf) {
      acc2[qf][cf][0] = 0.f; acc2[qf][cf][1] = 0.f;
      acc2[qf][cf][2] = 0.f; acc2[qf][cf][3] = 0.f;
    }
  const __hip_bfloat16* bp2 = memT + (size_t)(c0 + lm) * M_ + g * 8;
  const int arow = t >> 4;
  float* oa = out_a + (size_t)(b * N_ + n0 + arow) * M_ + (t & 15) * 4;

  #pragma unroll
  for (int it = 0; it < 32; ++it) {
    const int k = it * 32;
    bf16x8 a2[4], b2[3];
    #pragma unroll
    for (int qf = 0; qf < 4; ++qf) {
      const int row = qf * 16 + lm;
      a2[qf] = *(const bf16x8*)(Pt + row * 2048 + (((k + g * 8) * 2) ^ ((row & 15) << 4)));
    }
    #pragma unroll
    for (int cf = 0; cf < 3; ++cf) b2[cf] = *(const bf16x8*)(bp2 + (size_t)cf * 16 * M_ + k);
    #pragma unroll
    for (int qf = 0; qf < 4; ++qf)
      #pragma unroll
      for (int cf = 0; cf < 3; ++cf)
        acc2[qf][cf] = __builtin_amdgcn_mfma_f32_16x16x32_bf16(a2[qf], b2[cf], acc2[qf][cf], 0, 0, 0);
    if ((it & 1) == 0) {
      const int p = it >> 1;
      const int col = (t & 15) * 4 + p * 64;
      short4v pv = *(const short4v*)(Pt + arow * 2048 + ((col * 2) ^ ((arow & 15) << 4)));
      f32x4 ov;
      ov[0] = __uint_as_float(((unsigned)(unsigned short)pv[0]) << 16);
      ov[1] = __uint_as_float(((unsigned)(unsigned short)pv[1]) << 16);
      ov[2] = __uint_as_float(((unsigned)(unsigned short)pv[2]) << 16);
      ov[3] = __uint_as_float(((unsigned)(unsigned short)pv[3]) << 16);
      *(f32x4*)(oa + p * 64) = ov;
    }
  }

  // transposed z_hat store: out_z[b][c][n]
  float* oz = out_z + (size_t)b * C_ * N_ + n0;
  #pragma unroll
  for (int qf = 0; qf < 4; ++qf)
    #pragma unroll
    for (int cf = 0; cf < 3; ++cf) {
      const int c = c0 + cf * 16 + lm;
      *(f32x4*)(oz + (size_t)c * N_ + qf * 16 + g * 4) = acc2[qf][cf];
    }
}

// ---------------------------------------------------------------------------
extern "C" void kernel_launch(void* const* d_in, const int* in_sizes, int n_in,
                              void* d_out, int out_size, void* d_ws, size_t ws_size,
                              hipStream_t stream) {
  const float* z = (const float*)d_in[0];
  const float* mem = (const float*)d_in[1];
  float* out_z = (float*)d_out;
  float* out_a = out_z + (size_t)B_ * C_ * N_;

  char* ws = (char*)d_ws;
  __hip_bfloat16* zb     = (__hip_bfloat16*)ws;                         // 96 MB
  __hip_bfloat16* mem_bf = (__hip_bfloat16*)(ws + (size_t)100663296);   // 1.5 MB
  __hip_bfloat16* memT   = (__hip_bfloat16*)(ws + (size_t)100663296 + 1572864);
  float* rz              = (float*)(ws + (size_t)100663296 + 2 * 1572864);
  float* rm              = (float*)(ws + (size_t)100663296 + 2 * 1572864 + 262144);

  (void)hipFuncSetAttribute((const void*)fused_attn_kernel,
                            hipFuncAttributeMaxDynamicSharedMemorySize, SMEM_BYTES);

  prep_mem_kernel<<<dim3(M_), dim3(256), 0, stream>>>(mem, mem_bf, memT, rm);
  prep_z_kernel<<<dim3(B_ * (N_ / 64)), dim3(256), 0, stream>>>(z, zb, rz);
  fused_attn_kernel<<<dim3(B_ * (N_ / 64)), dim3(1024), SMEM_BYTES, stream>>>(
      zb, mem_bf, memT, rz, rm, out_z, out_a);
}

// Round 4
// 772.648 us; speedup vs baseline: 1.3994x; 1.3059x over previous
//
#include <hip/hip_runtime.h>
#include <hip/hip_bf16.h>

typedef __attribute__((ext_vector_type(8))) short bf16x8;
typedef __attribute__((ext_vector_type(4))) short short4v;
typedef __attribute__((ext_vector_type(4))) float f32x4;
typedef __attribute__((ext_vector_type(16))) float f32x16;
typedef __attribute__((ext_vector_type(4))) unsigned int uint4v;

#define B_ 16
#define C_ 768
#define N_ 4096
#define M_ 1024

// ---------------------------------------------------------------------------
// prep_mem: memory (M,C) fp32 ->
//   memF  [96 kb][1024 m][8]  bf16   (phase-1 B fragments: unit = mem[m][8kb..+7])
//   memTF [128 kb][768 c][8]  bf16   (phase-2 B fragments: unit = mem[8kb..+7][c])
//   rmss  [1024] f32 = sum of squares per memory row (rsqrt done in fused)
// Blocks 0..511: memF + rmss (2 m-rows each). Blocks 512..639: memTF (1 kb each).
// ---------------------------------------------------------------------------
__global__ __launch_bounds__(256) void prep_mem_kernel(
    const float* __restrict__ mem, __hip_bfloat16* __restrict__ memF,
    __hip_bfloat16* __restrict__ memTF, float* __restrict__ rmss)
{
  const int t = threadIdx.x;
  if (blockIdx.x < 512) {
    const int mrow = t >> 7;          // 0..1
    const int u = t & 127;            // unit (kb) index, 96 active
    const int m = blockIdx.x * 2 + mrow;
    __shared__ float sred[2][128];
    float ss = 0.f;
    if (u < 96) {
      const float* mp = mem + (size_t)m * C_ + u * 8;
      f32x4 v0 = *(const f32x4*)mp;
      f32x4 v1 = *(const f32x4*)(mp + 4);
      ss = v0[0]*v0[0] + v0[1]*v0[1] + v0[2]*v0[2] + v0[3]*v0[3]
         + v1[0]*v1[0] + v1[1]*v1[1] + v1[2]*v1[2] + v1[3]*v1[3];
      alignas(16) __hip_bfloat16 hh[8];
      hh[0] = __float2bfloat16(v0[0]); hh[1] = __float2bfloat16(v0[1]);
      hh[2] = __float2bfloat16(v0[2]); hh[3] = __float2bfloat16(v0[3]);
      hh[4] = __float2bfloat16(v1[0]); hh[5] = __float2bfloat16(v1[1]);
      hh[6] = __float2bfloat16(v1[2]); hh[7] = __float2bfloat16(v1[3]);
      *(uint4v*)(memF + ((size_t)u * M_ + m) * 8) = *(const uint4v*)hh;
    }
    sred[mrow][u] = ss;
    __syncthreads();
    #pragma unroll
    for (int s = 64; s > 0; s >>= 1) {
      if (u < s) sred[mrow][u] += sred[mrow][u + s];
      __syncthreads();
    }
    if (u == 0) rmss[m] = sred[mrow][0];
  } else {
    const int kb = blockIdx.x - 512;  // 0..127
    #pragma unroll
    for (int rep = 0; rep < 3; ++rep) {
      const int c = t + rep * 256;
      alignas(16) __hip_bfloat16 hh[8];
      #pragma unroll
      for (int j = 0; j < 8; ++j)
        hh[j] = __float2bfloat16(mem[(size_t)(8 * kb + j) * C_ + c]);
      *(uint4v*)(memTF + ((size_t)kb * C_ + c) * 8) = *(const uint4v*)hh;
    }
  }
}

// ---------------------------------------------------------------------------
// fused_attn: block = (b, 64 q-rows), 1024 threads = 16 waves.
// Stage: z fp32 (B,C,N) -> bf16 fragment-layout LDS At[96 kb][64 n][8] + rz.
// Phase 1 (32x32x16): wave w owns m-chunk [w*64,+64); A from LDS, B from memF
//   (coalesced fragment loads). exp without max-subtraction (cosine-bounded).
// P -> LDS fragment layout Pt[128 kb][64 q][8] (bf16, normalized).
// Phase 2 (16x16x32): wave w owns c-chunk [w*48,+48); B from memTF; attn fp32
//   written via vectorized LDS readback interleaved into the K-loop.
// ---------------------------------------------------------------------------
#define SMEM_BYTES 139776
#define O_RED 131072   // [64][16] f32
#define O_SRZ 135424   // [64] f32
#define O_SRM 135680   // [1024] f32

__global__ __launch_bounds__(1024, 4) void fused_attn_kernel(
    const float* __restrict__ z, const __hip_bfloat16* __restrict__ memF,
    const __hip_bfloat16* __restrict__ memTF, const float* __restrict__ rmss,
    float* __restrict__ out_z, float* __restrict__ out_a)
{
  extern __shared__ char smem[];
  const int b = blockIdx.x >> 6;
  const int n0 = (blockIdx.x & 63) << 6;
  const int t = threadIdx.x;
  const int w = t >> 6, l = t & 63, lo = l & 31, hi = l >> 5;

  float* red = (float*)(smem + O_RED);
  float* srz = (float*)(smem + O_SRZ);
  float* srm = (float*)(smem + O_SRM);

  // ---- stage A-tile: z fp32 -> bf16 fragment LDS + sumsq ----
  {
    const int n = t & 63;             // lane dim (wave-uniform cg)
    const int cg = t >> 6;            // 0..15, 48 c's each
    const float* zp = z + (size_t)b * C_ * N_ + (size_t)(cg * 48) * N_ + n0 + n;
    float ss = 0.f;
    #pragma unroll
    for (int j = 0; j < 6; ++j) {
      alignas(16) __hip_bfloat16 hh[8];
      #pragma unroll
      for (int i = 0; i < 8; ++i) {
        float v = zp[(size_t)(j * 8 + i) * N_];
        ss += v * v;
        hh[i] = __float2bfloat16(v);
      }
      *(uint4v*)(smem + ((cg * 6 + j) * 64 + n) * 16) = *(const uint4v*)hh;
    }
    red[n * 16 + cg] = ss;
    srm[t] = __builtin_amdgcn_rsqf(fmaxf(rmss[t], 1e-24f));
  }
  __syncthreads();
  if (t < 64) {
    float s = 0.f;
    #pragma unroll
    for (int i = 0; i < 16; ++i) s += red[t * 16 + i];
    srz[t] = __builtin_amdgcn_rsqf(fmaxf(s, 1e-24f));
  }
  __syncthreads();

  // ---- phase 1: raw scores via MFMA ----
  const int m0 = w << 6;
  f32x16 acc[2][2];
  #pragma unroll
  for (int qf = 0; qf < 2; ++qf)
    #pragma unroll
    for (int mf = 0; mf < 2; ++mf)
      #pragma unroll
      for (int j = 0; j < 16; ++j) acc[qf][mf][j] = 0.f;

  {
    const bf16x8* AtU = (const bf16x8*)smem;
    const bf16x8* BF = (const bf16x8*)memF;
    #pragma unroll
    for (int kb = 0; kb < 96; kb += 2) {
      bf16x8 a0 = AtU[(kb + hi) * 64 + lo];
      bf16x8 a1 = AtU[(kb + hi) * 64 + 32 + lo];
      bf16x8 b0 = BF[(size_t)(kb + hi) * M_ + m0 + lo];
      bf16x8 b1 = BF[(size_t)(kb + hi) * M_ + m0 + 32 + lo];
      acc[0][0] = __builtin_amdgcn_mfma_f32_32x32x16_bf16(a0, b0, acc[0][0], 0, 0, 0);
      acc[0][1] = __builtin_amdgcn_mfma_f32_32x32x16_bf16(a0, b1, acc[0][1], 0, 0, 0);
      acc[1][0] = __builtin_amdgcn_mfma_f32_32x32x16_bf16(a1, b0, acc[1][0], 0, 0, 0);
      acc[1][1] = __builtin_amdgcn_mfma_f32_32x32x16_bf16(a1, b1, acc[1][1], 0, 0, 0);
    }
  }

  // ---- epilogue: scale -> exp -> cross-wave row-sum ----
  float scm0 = srm[m0 + lo], scm1 = srm[m0 + 32 + lo];
  float rs[2][16];
  #pragma unroll
  for (int qf = 0; qf < 2; ++qf)
    #pragma unroll
    for (int r = 0; r < 16; ++r) {
      const int row = qf * 32 + (r & 3) + 8 * (r >> 2) + 4 * hi;
      const float sz = srz[row];
      float p0 = __expf(acc[qf][0][r] * sz * scm0);
      float p1 = __expf(acc[qf][1][r] * sz * scm1);
      acc[qf][0][r] = p0;
      acc[qf][1][r] = p1;
      rs[qf][r] = p0 + p1;
    }
  #pragma unroll
  for (int off = 1; off < 32; off <<= 1)
    #pragma unroll
    for (int qf = 0; qf < 2; ++qf)
      #pragma unroll
      for (int r = 0; r < 16; ++r)
        rs[qf][r] += __shfl_xor(rs[qf][r], off, 64);

  __syncthreads();   // At reads done; smem[0,131072) free for P
  if (lo == 0) {
    #pragma unroll
    for (int qf = 0; qf < 2; ++qf)
      #pragma unroll
      for (int r = 0; r < 16; ++r) {
        const int row = qf * 32 + (r & 3) + 8 * (r >> 2) + 4 * hi;
        red[row * 16 + w] = rs[qf][r];
      }
  }
  __syncthreads();
  float riv0 = 0.f;
  if (t < 64) {
    float s = 0.f;
    #pragma unroll
    for (int i = 0; i < 16; ++i) s += red[t * 16 + i];
    riv0 = 1.f / s;
  }
  __syncthreads();
  if (t < 64) srz[t] = riv0;   // reuse srz as 1/rowsum
  __syncthreads();

  // ---- write normalized P bf16 into fragment-layout LDS ----
  char* Ptb = smem;
  #pragma unroll
  for (int qf = 0; qf < 2; ++qf)
    #pragma unroll
    for (int r = 0; r < 16; ++r) {
      const int row = qf * 32 + (r & 3) + 8 * (r >> 2) + 4 * hi;
      const float riv = srz[row];
      #pragma unroll
      for (int mf = 0; mf < 2; ++mf) {
        const int col = m0 + mf * 32 + lo;
        *(__hip_bfloat16*)(Ptb + ((col >> 3) * 64 + row) * 16 + (col & 7) * 2) =
            __float2bfloat16(acc[qf][mf][r] * riv);
      }
    }
  __syncthreads();

  // ---- phase 2: z_hat = P @ memory + interleaved attn stores ----
  const int c0 = w * 48;
  const int lm = l & 15, g = l >> 4;
  f32x4 acc2[4][3];
  #pragma unroll
  for (int qf = 0; qf < 4; ++qf)
    #pragma unroll
    for (int cf = 0; cf < 3; ++cf) {
      acc2[qf][cf][0] = 0.f; acc2[qf][cf][1] = 0.f;
      acc2[qf][cf][2] = 0.f; acc2[qf][cf][3] = 0.f;
    }
  const bf16x8* PtU = (const bf16x8*)smem;
  const bf16x8* BT = (const bf16x8*)memTF;
  const int arow = t >> 4;
  float* oa = out_a + (size_t)(b * N_ + n0 + arow) * M_ + (t & 15) * 4;

  #pragma unroll
  for (int it = 0; it < 32; ++it) {
    const int kb = it * 4;
    bf16x8 a2[4], b2[3];
    #pragma unroll
    for (int qf = 0; qf < 4; ++qf)
      a2[qf] = PtU[(kb + g) * 64 + qf * 16 + lm];
    #pragma unroll
    for (int cf = 0; cf < 3; ++cf)
      b2[cf] = BT[(size_t)(kb + g) * C_ + c0 + cf * 16 + lm];
    #pragma unroll
    for (int qf = 0; qf < 4; ++qf)
      #pragma unroll
      for (int cf = 0; cf < 3; ++cf)
        acc2[qf][cf] = __builtin_amdgcn_mfma_f32_16x16x32_bf16(a2[qf], b2[cf], acc2[qf][cf], 0, 0, 0);
    if ((it & 1) == 0) {
      const int p = it >> 1;
      const int colb = (t & 15) * 4 + p * 64;
      short4v pv = *(const short4v*)(Ptb + ((colb >> 3) * 64 + arow) * 16 + (colb & 7) * 2);
      f32x4 ov;
      ov[0] = __uint_as_float(((unsigned)(unsigned short)pv[0]) << 16);
      ov[1] = __uint_as_float(((unsigned)(unsigned short)pv[1]) << 16);
      ov[2] = __uint_as_float(((unsigned)(unsigned short)pv[2]) << 16);
      ov[3] = __uint_as_float(((unsigned)(unsigned short)pv[3]) << 16);
      *(f32x4*)(oa + p * 64) = ov;
    }
  }

  // transposed z_hat store: out_z[b][c][n]
  float* oz = out_z + (size_t)b * C_ * N_ + n0;
  #pragma unroll
  for (int qf = 0; qf < 4; ++qf)
    #pragma unroll
    for (int cf = 0; cf < 3; ++cf) {
      const int c = c0 + cf * 16 + lm;
      *(f32x4*)(oz + (size_t)c * N_ + qf * 16 + g * 4) = acc2[qf][cf];
    }
}

// ---------------------------------------------------------------------------
extern "C" void kernel_launch(void* const* d_in, const int* in_sizes, int n_in,
                              void* d_out, int out_size, void* d_ws, size_t ws_size,
                              hipStream_t stream) {
  const float* z = (const float*)d_in[0];
  const float* mem = (const float*)d_in[1];
  float* out_z = (float*)d_out;
  float* out_a = out_z + (size_t)B_ * C_ * N_;

  char* ws = (char*)d_ws;
  __hip_bfloat16* memF  = (__hip_bfloat16*)ws;                       // 1.5 MB
  __hip_bfloat16* memTF = (__hip_bfloat16*)(ws + 1572864);           // 1.5 MB
  float* rmss           = (float*)(ws + 2 * 1572864);                // 4 KB

  (void)hipFuncSetAttribute((const void*)fused_attn_kernel,
                            hipFuncAttributeMaxDynamicSharedMemorySize, SMEM_BYTES);

  prep_mem_kernel<<<dim3(640), dim3(256), 0, stream>>>(mem, memF, memTF, rmss);
  fused_attn_kernel<<<dim3(B_ * (N_ / 64)), dim3(1024), SMEM_BYTES, stream>>>(
      z, memF, memTF, rmss, out_z, out_a);
}